// Round 1
// baseline (332.685 us; speedup 1.0000x reference)
//
#include <hip/hip_runtime.h>
#include <hip/hip_bf16.h>

// DeformableAttention on MI355X.
// Pipeline: gemm(q) -> conv+LN+GELU+offset->pos -> grid_sample->xs ->
//           gemm(kv) -> fused flash-attn with on-the-fly rpe bias -> gemm(out)
// f32 everywhere except attention QK^T / PV which use bf16 MFMA (f32 accum).

#define B_   8
#define N_   1024
#define DIM_ 256
#define DG_  128
#define NG_  2
#define NH_  8
#define DH_  32
#define EPS_ 1e-5f
#define ASCALE 0.17677669529663687f  // 1/sqrt(32)

typedef __attribute__((ext_vector_type(8))) short bf16x8;
typedef __attribute__((ext_vector_type(4))) float f32x4;

__device__ __forceinline__ short f2bf(float f) {
  union { float f; unsigned u; } v; v.f = f;
  unsigned r = (v.u + 0x7fffu + ((v.u >> 16) & 1u)) >> 16;  // RNE
  return (short)r;
}
__device__ __forceinline__ float bf2f(short s) {
  union { unsigned u; float f; } v;
  v.u = ((unsigned)(unsigned short)s) << 16;
  return v.f;
}

// ---------------------------------------------------------------------------
// Generic f32 GEMM: C[M,N] = A[M,K] @ B[K,N] (+bias).  M,N,K multiples of 64/16.
// 64x64 tile, BK=16, 256 threads, 4x4 micro-tile.
// ---------------------------------------------------------------------------
__global__ __launch_bounds__(256) void gemm_f32(
    const float* __restrict__ A, const float* __restrict__ B,
    float* __restrict__ C, const float* __restrict__ bias,
    int M, int N, int K)
{
  __shared__ __align__(16) float As[16][68];
  __shared__ __align__(16) float Bs[16][64];
  const int t = threadIdx.x;
  const int n0 = blockIdx.x << 6, m0 = blockIdx.y << 6;
  const int ty = t >> 4, tx = t & 15;
  const int am = t >> 2, ak = (t & 3) << 2;
  const int bk = t >> 4, bn = (t & 15) << 2;
  float acc[4][4] = {};
  for (int k0 = 0; k0 < K; k0 += 16) {
    float4 av = *(const float4*)&A[(size_t)(m0 + am) * K + k0 + ak];
    float4 bv = *(const float4*)&B[(size_t)(k0 + bk) * N + n0 + bn];
    As[ak + 0][am] = av.x; As[ak + 1][am] = av.y;
    As[ak + 2][am] = av.z; As[ak + 3][am] = av.w;
    *(float4*)&Bs[bk][bn] = bv;
    __syncthreads();
#pragma unroll
    for (int kk = 0; kk < 16; kk++) {
      float4 a = *(const float4*)&As[kk][ty << 2];
      float4 b4 = *(const float4*)&Bs[kk][tx << 2];
      float avr[4] = {a.x, a.y, a.z, a.w};
      float bvr[4] = {b4.x, b4.y, b4.z, b4.w};
#pragma unroll
      for (int ii = 0; ii < 4; ii++)
#pragma unroll
        for (int jj = 0; jj < 4; jj++)
          acc[ii][jj] = fmaf(avr[ii], bvr[jj], acc[ii][jj]);
    }
    __syncthreads();
  }
  float badd[4] = {0.f, 0.f, 0.f, 0.f};
  if (bias) {
#pragma unroll
    for (int jj = 0; jj < 4; jj++) badd[jj] = bias[n0 + (tx << 2) + jj];
  }
#pragma unroll
  for (int ii = 0; ii < 4; ii++) {
    float4 o;
    o.x = acc[ii][0] + badd[0]; o.y = acc[ii][1] + badd[1];
    o.z = acc[ii][2] + badd[2]; o.w = acc[ii][3] + badd[3];
    *(float4*)&C[(size_t)(m0 + (ty << 2) + ii) * N + n0 + (tx << 2)] = o;
  }
}

// ---------------------------------------------------------------------------
// Fused depthwise conv5x5 + LayerNorm(128) + GELU + @Woff + tanh -> pos (y,x)
// One block (128 threads, one per channel) per (bg, pixel).
// ---------------------------------------------------------------------------
__device__ __forceinline__ float block_sum_128(float v, float* red) {
#pragma unroll
  for (int o = 32; o > 0; o >>= 1) v += __shfl_down(v, o);
  __syncthreads();  // protect red[] reuse across calls
  if ((threadIdx.x & 63) == 0) red[threadIdx.x >> 6] = v;
  __syncthreads();
  return red[0] + red[1];
}

__global__ __launch_bounds__(128) void conv_pos_kernel(
    const float* __restrict__ q, const float* __restrict__ conv_w,
    const float* __restrict__ conv_b, const float* __restrict__ ln_g,
    const float* __restrict__ ln_b, const float* __restrict__ Woff,
    float* __restrict__ pos)
{
  __shared__ float red[2];
  const int bg = blockIdx.x >> 10;
  const int pix = blockIdx.x & 1023;
  const int hh = pix >> 5, ww = pix & 31;
  const int b = bg >> 1, g = bg & 1;
  const int c = threadIdx.x;

  const float* wgt = conv_w + c * 25;
  float acc = conv_b[c];
#pragma unroll
  for (int dy = 0; dy < 5; dy++) {
    int y = hh + dy - 2;
    if ((unsigned)y < 32u) {
#pragma unroll
      for (int dx = 0; dx < 5; dx++) {
        int x = ww + dx - 2;
        if ((unsigned)x < 32u)
          acc = fmaf(q[(size_t)((b << 10) + (y << 5) + x) * 256 + (g << 7) + c],
                     wgt[dy * 5 + dx], acc);
      }
    }
  }
  float s = block_sum_128(acc, red);
  float mu = s * (1.f / 128.f);
  float d = acc - mu;
  float vs = block_sum_128(d * d, red);
  float inv = rsqrtf(vs * (1.f / 128.f) + EPS_);
  float val = d * inv * ln_g[c] + ln_b[c];
  float ge = 0.5f * val * (1.f + erff(val * 0.70710678118654752f));
  float o0 = block_sum_128(ge * Woff[2 * c], red);
  float o1 = block_sum_128(ge * Woff[2 * c + 1], red);
  if (c == 0) {
    float py = tanhf(o0) * 0.0625f + ((hh + 0.5f) * 0.0625f - 1.f);
    float px = tanhf(o1) * 0.0625f + ((ww + 0.5f) * 0.0625f - 1.f);
    ((float2*)pos)[(bg << 10) + pix] = make_float2(py, px);
  }
}

// ---------------------------------------------------------------------------
// grid_sample of xg (= q regrouped) at pos -> x_sampled (B,N,256)
// One block per (b,n); thread = channel d (g = d>>7).
// ---------------------------------------------------------------------------
__global__ __launch_bounds__(256) void sample_kernel(
    const float* __restrict__ q, const float* __restrict__ pos,
    float* __restrict__ xs)
{
  const int n = blockIdx.x & 1023, b = blockIdx.x >> 10;
  const int d = threadIdx.x;
  const int g = d >> 7;
  float2 p = ((const float2*)pos)[(((b << 1) + g) << 10) + n];
  float x = (p.y + 1.f) * 15.5f;   // grid[...,0] = pos[...,1] (x)
  float y = (p.x + 1.f) * 15.5f;
  float x0f = floorf(x), y0f = floorf(y);
  int ix0 = (int)x0f, iy0 = (int)y0f;
  float fx = x - x0f, fy = y - y0f;
  float acc = 0.f;
#pragma unroll
  for (int dy = 0; dy < 2; dy++) {
#pragma unroll
    for (int dx = 0; dx < 2; dx++) {
      int yi = iy0 + dy, xi = ix0 + dx;
      float w = (dy ? fy : 1.f - fy) * (dx ? fx : 1.f - fx);
      if ((unsigned)yi < 32u && (unsigned)xi < 32u)
        acc = fmaf(w, q[(size_t)((b << 10) + (yi << 5) + xi) * 256 + d], acc);
    }
  }
  xs[(size_t)((b << 10) + n) * 256 + d] = acc;
}

// ---------------------------------------------------------------------------
// Fused attention: per (i-tile 64, head, batch).  bf16 MFMA 16x16x32 for
// QK^T and PV; bias bilinear-sampled from rpe channel h (LDS) on the fly;
// online softmax with rows resident in registers (S/O share C/D row layout).
// ---------------------------------------------------------------------------
__global__ __launch_bounds__(256) void attn_kernel(
    const float* __restrict__ q, const float* __restrict__ kv,
    const float* __restrict__ pos, const float* __restrict__ rpe,
    float* __restrict__ ao)
{
  const int it = blockIdx.x;   // i-tile (64 rows)
  const int h  = blockIdx.y;
  const int b  = blockIdx.z;
  const int g  = h >> 2;
  const int t  = threadIdx.x;
  const int wv = t >> 6;          // wave 0..3 -> rows 16*wv..16*wv+15
  const int l16 = t & 15;
  const int quad = (t & 63) >> 4;

  // row strides chosen = 4 mod 8 words so 8-lane b128 groups are conflict-free
  __shared__ __align__(16) short Qs[64 * 40];
  __shared__ __align__(16) short Ks[64 * 40];
  __shared__ __align__(16) short Vt[32 * 72];   // V transposed [d][j]
  __shared__ __align__(16) short PL[64 * 72];   // P [i][j] bf16
  __shared__ float2 posT[64];
  __shared__ __align__(16) float rpebuf[64 + 3969 + 67];  // zero pads: clamped
  float* rpeL = rpebuf + 64;                              // reads are mask-safe

  // zero the pads (disjoint from center; barrier comes from staging syncs)
  if (t < 64) rpebuf[t] = 0.f;
  if (t < 67) rpebuf[64 + 3969 + t] = 0.f;
  for (int i = t; i < 3969; i += 256) rpeL[i] = rpe[h * 3969 + i];

  // stage Q (once), scaled, bf16
  {
    int i = t >> 2, dq = (t & 3) << 3;
    const float* src = q + (size_t)((b << 10) + (it << 6) + i) * 256 + (h << 5) + dq;
    float4 f0 = *(const float4*)src;
    float4 f1 = *(const float4*)(src + 4);
    bf16x8 v;
    v[0] = f2bf(f0.x * ASCALE); v[1] = f2bf(f0.y * ASCALE);
    v[2] = f2bf(f0.z * ASCALE); v[3] = f2bf(f0.w * ASCALE);
    v[4] = f2bf(f1.x * ASCALE); v[5] = f2bf(f1.y * ASCALE);
    v[6] = f2bf(f1.z * ASCALE); v[7] = f2bf(f1.w * ASCALE);
    *(bf16x8*)&Qs[i * 40 + dq] = v;
  }

  // per-row separable bias coords: ys = ay[i] + by[j], xs = ax[i] + bx[j]
  float ay[4], ax[4];
#pragma unroll
  for (int r = 0; r < 4; r++) {
    int qi = (it << 6) + (wv << 4) + (quad << 2) + r;
    int iy = qi >> 5, ix = qi & 31;
    ay[r] = 15.5f * ((iy + 0.5f) * 0.0625f - 1.f) + 31.f;
    ax[r] = 15.5f * ((ix + 0.5f) * 0.0625f - 1.f) + 31.f;
  }

  f32x4 Oacc[2] = {};
  float m_r[4], l_r[4];
#pragma unroll
  for (int r = 0; r < 4; r++) { m_r[r] = -3.0e38f; l_r[r] = 0.f; }

  for (int kt = 0; kt < 16; kt++) {
    const int jb = kt << 6;
    __syncthreads();  // prior PV done; (iter 0: Q/rpe staging also fenced)
    // stage K tile (bf16, row-major [j][32])
    {
      int j = t >> 2, dq = (t & 3) << 3;
      const float* src = kv + (size_t)((b << 10) + jb + j) * 512 + (h << 5) + dq;
      float4 f0 = *(const float4*)src;
      float4 f1 = *(const float4*)(src + 4);
      bf16x8 v;
      v[0] = f2bf(f0.x); v[1] = f2bf(f0.y); v[2] = f2bf(f0.z); v[3] = f2bf(f0.w);
      v[4] = f2bf(f1.x); v[5] = f2bf(f1.y); v[6] = f2bf(f1.z); v[7] = f2bf(f1.w);
      *(bf16x8*)&Ks[j * 40 + dq] = v;
    }
    // stage V transposed [d][j]
#pragma unroll
    for (int rr = 0; rr < 8; rr++) {
      int idx = t + (rr << 8);
      int j = idx >> 5, d = idx & 31;
      Vt[d * 72 + j] =
          f2bf(kv[(size_t)((b << 10) + jb + j) * 512 + 256 + (h << 5) + d]);
    }
    if (t < 64) posT[t] = ((const float2*)pos)[(((b << 1) + g) << 10) + jb + t];
    __syncthreads();

    // ---- QK^T: 4 MFMA (one per 16-wide j tile), K=32 covers full head dim
    bf16x8 aq = *(const bf16x8*)&Qs[((wv << 4) + l16) * 40 + (quad << 3)];
    f32x4 S[4];
#pragma unroll
    for (int jt = 0; jt < 4; jt++) {
      bf16x8 bk = *(const bf16x8*)&Ks[((jt << 4) + l16) * 40 + (quad << 3)];
      f32x4 z = {};
      S[jt] = __builtin_amdgcn_mfma_f32_16x16x32_bf16(aq, bk, z, 0, 0, 0);
    }

    // ---- bias + online softmax (S element: row=quad*4+r, col=jt*16+l16)
    float sv[4][4], mnew[4];
#pragma unroll
    for (int r = 0; r < 4; r++) mnew[r] = m_r[r];
#pragma unroll
    for (int jt = 0; jt < 4; jt++) {
      float2 pj = posT[(jt << 4) + l16];
      float by = -15.5f * pj.x;
      float bx = -15.5f * pj.y;
#pragma unroll
      for (int r = 0; r < 4; r++) {
        float ys = ay[r] + by, sx = ax[r] + bx;
        float y0f = floorf(ys), x0f = floorf(sx);
        float fy = ys - y0f, fx = sx - x0f;
        int iy0 = (int)y0f, ix0 = (int)x0f;
        int cy = min(max(iy0, -1), 62);
        int cx = min(max(ix0, -1), 62);
        int base = cy * 63 + cx;
        float g00 = rpeL[base], g01 = rpeL[base + 1];
        float g10 = rpeL[base + 63], g11 = rpeL[base + 64];
        float wx0 = ((unsigned)ix0 < 63u) ? (1.f - fx) : 0.f;
        float wx1 = ((unsigned)(ix0 + 1) < 63u) ? fx : 0.f;
        float wy0 = ((unsigned)iy0 < 63u) ? (1.f - fy) : 0.f;
        float wy1 = ((unsigned)(iy0 + 1) < 63u) ? fy : 0.f;
        float bias = wy0 * (wx0 * g00 + wx1 * g01) + wy1 * (wx0 * g10 + wx1 * g11);
        float s = S[jt][r] + bias;
        sv[jt][r] = s;
        mnew[r] = fmaxf(mnew[r], s);
      }
    }
#pragma unroll
    for (int r = 0; r < 4; r++) {
#pragma unroll
      for (int msk = 1; msk < 16; msk <<= 1)
        mnew[r] = fmaxf(mnew[r], __shfl_xor(mnew[r], msk));
    }
    float rowsum[4];
#pragma unroll
    for (int r = 0; r < 4; r++) {
      float alpha = __expf(m_r[r] - mnew[r]);
      m_r[r] = mnew[r];
      l_r[r] *= alpha;
      Oacc[0][r] *= alpha;
      Oacc[1][r] *= alpha;
      rowsum[r] = 0.f;
    }
#pragma unroll
    for (int jt = 0; jt < 4; jt++) {
#pragma unroll
      for (int r = 0; r < 4; r++) {
        float p = __expf(sv[jt][r] - m_r[r]);
        short pb = f2bf(p);
        rowsum[r] += bf2f(pb);  // sum the quantized p for consistency with PV
        PL[((wv << 4) + (quad << 2) + r) * 72 + (jt << 4) + l16] = pb;
      }
    }
#pragma unroll
    for (int r = 0; r < 4; r++) {
      float rs = rowsum[r];
#pragma unroll
      for (int msk = 1; msk < 16; msk <<= 1) rs += __shfl_xor(rs, msk);
      l_r[r] += rs;
    }
    __syncthreads();  // PL visible (cross-lane LDS within wave still needs fence)

    // ---- PV: O[16i x 32d] += P[16i x 64j] @ V[64j x 32d]   (4 MFMA)
    bf16x8 pa0 = *(const bf16x8*)&PL[((wv << 4) + l16) * 72 + (quad << 3)];
    bf16x8 pa1 = *(const bf16x8*)&PL[((wv << 4) + l16) * 72 + 32 + (quad << 3)];
#pragma unroll
    for (int dt = 0; dt < 2; dt++) {
      bf16x8 vb0 = *(const bf16x8*)&Vt[((dt << 4) + l16) * 72 + (quad << 3)];
      bf16x8 vb1 = *(const bf16x8*)&Vt[((dt << 4) + l16) * 72 + 32 + (quad << 3)];
      Oacc[dt] = __builtin_amdgcn_mfma_f32_16x16x32_bf16(pa0, vb0, Oacc[dt], 0, 0, 0);
      Oacc[dt] = __builtin_amdgcn_mfma_f32_16x16x32_bf16(pa1, vb1, Oacc[dt], 0, 0, 0);
    }
  }

  // epilogue: normalize + write (rows of O match rows of m/l in-register)
#pragma unroll
  for (int r = 0; r < 4; r++) {
    float inv = 1.f / l_r[r];
    int row = (it << 6) + (wv << 4) + (quad << 2) + r;
#pragma unroll
    for (int dt = 0; dt < 2; dt++) {
      ao[(size_t)((b << 10) + row) * 256 + (h << 5) + (dt << 4) + l16] =
          Oacc[dt][r] * inv;
    }
  }
}

// ---------------------------------------------------------------------------
extern "C" void kernel_launch(void* const* d_in, const int* in_sizes, int n_in,
                              void* d_out, int out_size, void* d_ws, size_t ws_size,
                              hipStream_t stream) {
  (void)in_sizes; (void)n_in; (void)out_size; (void)ws_size;
  const float* x      = (const float*)d_in[0];
  const float* Wq     = (const float*)d_in[1];
  const float* Wkv    = (const float*)d_in[2];
  const float* conv_w = (const float*)d_in[3];
  const float* conv_b = (const float*)d_in[4];
  const float* ln_g   = (const float*)d_in[5];
  const float* ln_b   = (const float*)d_in[6];
  const float* Woff   = (const float*)d_in[7];
  const float* rpe    = (const float*)d_in[8];
  const float* Wout   = (const float*)d_in[9];
  const float* bout   = (const float*)d_in[10];
  float* out = (float*)d_out;

  float* ws  = (float*)d_ws;
  float* q   = ws;                       // 8*1024*256   = 2M floats
  float* pos = q   + 8 * 1024 * 256;     // 16*1024*2    = 32K floats
  float* xs  = pos + 16 * 1024 * 2;      // 8*1024*256   = 2M floats
  float* kvb = xs  + 8 * 1024 * 256;     // 8*1024*512   = 4M floats
  float* ao  = xs;                       // overlay: xs dead after kv GEMM

  // 1. q = x @ Wq
  gemm_f32<<<dim3(4, 128), 256, 0, stream>>>(x, Wq, q, nullptr, 8192, 256, 256);
  // 2. conv + LN + GELU + Woff + tanh -> pos
  conv_pos_kernel<<<16384, 128, 0, stream>>>(q, conv_w, conv_b, ln_g, ln_b, Woff, pos);
  // 3. grid_sample -> xs
  sample_kernel<<<8192, 256, 0, stream>>>(q, pos, xs);
  // 4. kv = xs @ Wkv
  gemm_f32<<<dim3(8, 128), 256, 0, stream>>>(xs, Wkv, kvb, nullptr, 8192, 512, 256);
  // 5. fused attention with rpe bias -> ao
  attn_kernel<<<dim3(16, 8, 8), 256, 0, stream>>>(q, kvb, pos, rpe, ao);
  // 6. out = ao @ Wout + bout
  gemm_f32<<<dim3(4, 128), 256, 0, stream>>>(ao, Wout, out, bout, 8192, 256, 256);
}

// Round 2
// 280.207 us; speedup vs baseline: 1.1873x; 1.1873x over previous
//
#include <hip/hip_runtime.h>
#include <hip/hip_bf16.h>

// DeformableAttention on MI355X.
// gemm_f32(q) -> conv+LN+GELU+offset->pos -> sample->xs(bf16) ->
// gemm_bf16(kv, MFMA) -> fused flash-attn w/ on-the-fly rpe bias (bf16 MFMA)
// -> gemm_bf16(out, MFMA, +bias)

#define EPS_ 1e-5f
#define ASCALE 0.17677669529663687f  // 1/sqrt(32)

typedef __attribute__((ext_vector_type(8))) short bf16x8;
typedef __attribute__((ext_vector_type(4))) short bf16x4;
typedef __attribute__((ext_vector_type(4))) float f32x4;

__device__ __forceinline__ short f2bf(float f) {
  union { float f; unsigned u; } v; v.f = f;
  unsigned r = (v.u + 0x7fffu + ((v.u >> 16) & 1u)) >> 16;  // RNE
  return (short)r;
}
__device__ __forceinline__ float bf2f(short s) {
  union { unsigned u; float f; } v;
  v.u = ((unsigned)(unsigned short)s) << 16;
  return v.f;
}
__device__ __forceinline__ float ubf_lo(unsigned u) {
  union { unsigned u; float f; } v; v.u = u << 16; return v.f;
}
__device__ __forceinline__ float ubf_hi(unsigned u) {
  union { unsigned u; float f; } v; v.u = u & 0xffff0000u; return v.f;
}

// ---------------------------------------------------------------------------
// f32 GEMM (only for q = x @ Wq): 64x64 tile, BK=16, 256 thr, 4x4 micro.
// ---------------------------------------------------------------------------
__global__ __launch_bounds__(256) void gemm_f32(
    const float* __restrict__ A, const float* __restrict__ B,
    float* __restrict__ C, const float* __restrict__ bias,
    int M, int N, int K)
{
  __shared__ __align__(16) float As[16][68];
  __shared__ __align__(16) float Bs[16][64];
  const int t = threadIdx.x;
  const int n0 = blockIdx.x << 6, m0 = blockIdx.y << 6;
  const int ty = t >> 4, tx = t & 15;
  const int am = t >> 2, ak = (t & 3) << 2;
  const int bk = t >> 4, bn = (t & 15) << 2;
  float acc[4][4] = {};
  for (int k0 = 0; k0 < K; k0 += 16) {
    float4 av = *(const float4*)&A[(size_t)(m0 + am) * K + k0 + ak];
    float4 bv = *(const float4*)&B[(size_t)(k0 + bk) * N + n0 + bn];
    As[ak + 0][am] = av.x; As[ak + 1][am] = av.y;
    As[ak + 2][am] = av.z; As[ak + 3][am] = av.w;
    *(float4*)&Bs[bk][bn] = bv;
    __syncthreads();
#pragma unroll
    for (int kk = 0; kk < 16; kk++) {
      float4 a = *(const float4*)&As[kk][ty << 2];
      float4 b4 = *(const float4*)&Bs[kk][tx << 2];
      float avr[4] = {a.x, a.y, a.z, a.w};
      float bvr[4] = {b4.x, b4.y, b4.z, b4.w};
#pragma unroll
      for (int ii = 0; ii < 4; ii++)
#pragma unroll
        for (int jj = 0; jj < 4; jj++)
          acc[ii][jj] = fmaf(avr[ii], bvr[jj], acc[ii][jj]);
    }
    __syncthreads();
  }
  float badd[4] = {0.f, 0.f, 0.f, 0.f};
  if (bias) {
#pragma unroll
    for (int jj = 0; jj < 4; jj++) badd[jj] = bias[n0 + (tx << 2) + jj];
  }
#pragma unroll
  for (int ii = 0; ii < 4; ii++) {
    float4 o;
    o.x = acc[ii][0] + badd[0]; o.y = acc[ii][1] + badd[1];
    o.z = acc[ii][2] + badd[2]; o.w = acc[ii][3] + badd[3];
    *(float4*)&C[(size_t)(m0 + (ty << 2) + ii) * N + n0 + (tx << 2)] = o;
  }
}

// ---------------------------------------------------------------------------
// Weight prep: Wkvt[n][k] = bf16(Wkv[k][n]) (512x256); Woutt (256x256).
// ---------------------------------------------------------------------------
__global__ __launch_bounds__(256) void prep_weights(
    const float* __restrict__ Wkv, const float* __restrict__ Wout,
    short* __restrict__ Wkvt, short* __restrict__ Woutt)
{
  int bid = blockIdx.x, k = threadIdx.x;
  if (bid < 512) Wkvt[bid * 256 + k] = f2bf(Wkv[k * 512 + bid]);
  else { int n = bid - 512; Woutt[n * 256 + k] = f2bf(Wout[k * 256 + n]); }
}

// ---------------------------------------------------------------------------
// bf16 MFMA GEMM: C[M,N] = A[M,256]bf16 @ Bt[N,256]^T bf16 (+bias).
// 64x64 tile, 256 thr, wave w = 16-row slab, 4 MFMA per 32-K chunk.
// ---------------------------------------------------------------------------
__global__ __launch_bounds__(256) void gemm_bf16(
    const short* __restrict__ A, const short* __restrict__ Bt,
    float* __restrict__ Cf, short* __restrict__ Cb,
    const float* __restrict__ bias, int N)
{
  __shared__ __align__(16) short As[64 * 40];
  __shared__ __align__(16) short Bs[64 * 40];
  const int t = threadIdx.x;
  const int n0 = blockIdx.x << 6, m0 = blockIdx.y << 6;
  const int wv = t >> 6, l16 = t & 15, quad = (t & 63) >> 4;
  const int row = t >> 2, koff = (t & 3) << 3;
  f32x4 acc[4] = {};
  for (int k0 = 0; k0 < 256; k0 += 32) {
    bf16x8 av = *(const bf16x8*)&A[(size_t)(m0 + row) * 256 + k0 + koff];
    bf16x8 bv = *(const bf16x8*)&Bt[(size_t)(n0 + row) * 256 + k0 + koff];
    __syncthreads();  // prior-iter frag reads done before overwrite
    *(bf16x8*)&As[row * 40 + koff] = av;
    *(bf16x8*)&Bs[row * 40 + koff] = bv;
    __syncthreads();
    bf16x8 a = *(const bf16x8*)&As[((wv << 4) + l16) * 40 + (quad << 3)];
#pragma unroll
    for (int jt = 0; jt < 4; jt++) {
      bf16x8 bb = *(const bf16x8*)&Bs[((jt << 4) + l16) * 40 + (quad << 3)];
      acc[jt] = __builtin_amdgcn_mfma_f32_16x16x32_bf16(a, bb, acc[jt], 0, 0, 0);
    }
  }
#pragma unroll
  for (int jt = 0; jt < 4; jt++) {
#pragma unroll
    for (int r = 0; r < 4; r++) {
      int mrow = m0 + (wv << 4) + (quad << 2) + r;
      int ncol = n0 + (jt << 4) + l16;
      float v = acc[jt][r];
      if (bias) v += bias[ncol];
      if (Cf) Cf[(size_t)mrow * N + ncol] = v;
      else    Cb[(size_t)mrow * N + ncol] = f2bf(v);
    }
  }
}

// ---------------------------------------------------------------------------
// conv5x5 depthwise + LN(128) + GELU + @Woff + tanh -> pos
// ---------------------------------------------------------------------------
__device__ __forceinline__ float block_sum_128(float v, float* red) {
#pragma unroll
  for (int o = 32; o > 0; o >>= 1) v += __shfl_down(v, o);
  __syncthreads();
  if ((threadIdx.x & 63) == 0) red[threadIdx.x >> 6] = v;
  __syncthreads();
  return red[0] + red[1];
}

__global__ __launch_bounds__(128) void conv_pos_kernel(
    const float* __restrict__ q, const float* __restrict__ conv_w,
    const float* __restrict__ conv_b, const float* __restrict__ ln_g,
    const float* __restrict__ ln_b, const float* __restrict__ Woff,
    float* __restrict__ pos)
{
  __shared__ float red[2];
  const int bg = blockIdx.x >> 10;
  const int pix = blockIdx.x & 1023;
  const int hh = pix >> 5, ww = pix & 31;
  const int b = bg >> 1, g = bg & 1;
  const int c = threadIdx.x;

  const float* wgt = conv_w + c * 25;
  float acc = conv_b[c];
#pragma unroll
  for (int dy = 0; dy < 5; dy++) {
    int y = hh + dy - 2;
    if ((unsigned)y < 32u) {
#pragma unroll
      for (int dx = 0; dx < 5; dx++) {
        int x = ww + dx - 2;
        if ((unsigned)x < 32u)
          acc = fmaf(q[(size_t)((b << 10) + (y << 5) + x) * 256 + (g << 7) + c],
                     wgt[dy * 5 + dx], acc);
      }
    }
  }
  float s = block_sum_128(acc, red);
  float mu = s * (1.f / 128.f);
  float d = acc - mu;
  float vs = block_sum_128(d * d, red);
  float inv = rsqrtf(vs * (1.f / 128.f) + EPS_);
  float val = d * inv * ln_g[c] + ln_b[c];
  float ge = 0.5f * val * (1.f + erff(val * 0.70710678118654752f));
  float o0 = block_sum_128(ge * Woff[2 * c], red);
  float o1 = block_sum_128(ge * Woff[2 * c + 1], red);
  if (c == 0) {
    float py = tanhf(o0) * 0.0625f + ((hh + 0.5f) * 0.0625f - 1.f);
    float px = tanhf(o1) * 0.0625f + ((ww + 0.5f) * 0.0625f - 1.f);
    ((float2*)pos)[(bg << 10) + pix] = make_float2(py, px);
  }
}

// ---------------------------------------------------------------------------
// grid_sample -> xs (bf16)
// ---------------------------------------------------------------------------
__global__ __launch_bounds__(256) void sample_kernel(
    const float* __restrict__ q, const float* __restrict__ pos,
    short* __restrict__ xsb)
{
  const int n = blockIdx.x & 1023, b = blockIdx.x >> 10;
  const int d = threadIdx.x;
  const int g = d >> 7;
  float2 p = ((const float2*)pos)[(((b << 1) + g) << 10) + n];
  float x = (p.y + 1.f) * 15.5f;
  float y = (p.x + 1.f) * 15.5f;
  float x0f = floorf(x), y0f = floorf(y);
  int ix0 = (int)x0f, iy0 = (int)y0f;
  float fx = x - x0f, fy = y - y0f;
  float acc = 0.f;
#pragma unroll
  for (int dy = 0; dy < 2; dy++) {
#pragma unroll
    for (int dx = 0; dx < 2; dx++) {
      int yi = iy0 + dy, xi = ix0 + dx;
      float w = (dy ? fy : 1.f - fy) * (dx ? fx : 1.f - fx);
      if ((unsigned)yi < 32u && (unsigned)xi < 32u)
        acc = fmaf(w, q[(size_t)((b << 10) + (yi << 5) + xi) * 256 + d], acc);
    }
  }
  xsb[(size_t)((b << 10) + n) * 256 + d] = f2bf(acc);
}

// ---------------------------------------------------------------------------
// Fused attention. K/V from bf16 kv; rpe packed as bf16 pairs (1 b32 read =
// both x-adjacent taps); P aliased into the K buffer (K dead after QK^T,
// P A-frag rows are wave-local -> no extra barrier between P write and read).
// ---------------------------------------------------------------------------
__global__ __launch_bounds__(256) void attn_kernel(
    const float* __restrict__ q, const short* __restrict__ kvb,
    const float* __restrict__ pos, const float* __restrict__ rpe,
    short* __restrict__ ao)
{
  const int it = blockIdx.x, h = blockIdx.y, b = blockIdx.z;
  const int g = h >> 2, t = threadIdx.x;
  const int wv = t >> 6, l16 = t & 15, quad = (t & 63) >> 4;

  __shared__ __align__(16) short Qs[64 * 40];
  __shared__ __align__(16) short KsP[64 * 72];   // K tile, then P (aliased)
  __shared__ __align__(16) short Vt[32 * 72];    // V transposed [d][j]
  __shared__ float2 posT[64];
  __shared__ __align__(16) unsigned rpebuf[64 + 3969 + 64];  // bf16 pairs
  unsigned* rpeU = rpebuf + 64;

  // stage rpe as (rpe[i], rpe[i+1]) bf16 pairs; zero pads make masked
  // out-of-grid taps read finite values
  if (t < 64) { rpebuf[t] = 0u; rpebuf[64 + 3969 + t] = 0u; }
  for (int i = t; i < 3969; i += 256) {
    float v0 = rpe[h * 3969 + i];
    float v1 = (i + 1 < 3969) ? rpe[h * 3969 + i + 1] : 0.f;
    rpebuf[64 + i] = ((unsigned)(unsigned short)f2bf(v0)) |
                     (((unsigned)(unsigned short)f2bf(v1)) << 16);
  }
  // stage Q (once), scaled, bf16
  {
    int i = t >> 2, dq = (t & 3) << 3;
    const float* src = q + (size_t)((b << 10) + (it << 6) + i) * 256 + (h << 5) + dq;
    float4 f0 = *(const float4*)src;
    float4 f1 = *(const float4*)(src + 4);
    bf16x8 v;
    v[0] = f2bf(f0.x * ASCALE); v[1] = f2bf(f0.y * ASCALE);
    v[2] = f2bf(f0.z * ASCALE); v[3] = f2bf(f0.w * ASCALE);
    v[4] = f2bf(f1.x * ASCALE); v[5] = f2bf(f1.y * ASCALE);
    v[6] = f2bf(f1.z * ASCALE); v[7] = f2bf(f1.w * ASCALE);
    *(bf16x8*)&Qs[i * 40 + dq] = v;
  }

  float ay[4], ax[4];
#pragma unroll
  for (int r = 0; r < 4; r++) {
    int qi = (it << 6) + (wv << 4) + (quad << 2) + r;
    int iy = qi >> 5, ix = qi & 31;
    ay[r] = 15.5f * ((iy + 0.5f) * 0.0625f - 1.f) + 31.f;
    ax[r] = 15.5f * ((ix + 0.5f) * 0.0625f - 1.f) + 31.f;
  }

  f32x4 Oacc[2] = {};
  float m_r[4], l_r[4];
#pragma unroll
  for (int r = 0; r < 4; r++) { m_r[r] = -3.0e38f; l_r[r] = 0.f; }

  for (int kt = 0; kt < 16; kt++) {
    const int jb = kt << 6;
    __syncthreads();  // [b1] prior PV reads of KsP/Vt done
    {   // K tile: straight bf16 copy [j][32]
      int j = t >> 2, koff = (t & 3) << 3;
      bf16x8 kvv = *(const bf16x8*)&kvb[(size_t)((b << 10) + jb + j) * 512 + (h << 5) + koff];
      *(bf16x8*)&KsP[j * 72 + koff] = kvv;
    }
#pragma unroll
    for (int iter = 0; iter < 2; iter++) {  // V transposed [d][j]
      int j = (t >> 3) + (iter << 5), d0 = (t & 7) << 2;
      bf16x4 vv = *(const bf16x4*)&kvb[(size_t)((b << 10) + jb + j) * 512 + 256 + (h << 5) + d0];
#pragma unroll
      for (int i2 = 0; i2 < 4; i2++) Vt[(d0 + i2) * 72 + j] = vv[i2];
    }
    if (t < 64) posT[t] = ((const float2*)pos)[(((b << 1) + g) << 10) + jb + t];
    __syncthreads();  // [b2]

    // ---- QK^T
    bf16x8 aq = *(const bf16x8*)&Qs[((wv << 4) + l16) * 40 + (quad << 3)];
    f32x4 S[4];
#pragma unroll
    for (int jt = 0; jt < 4; jt++) {
      bf16x8 bk = *(const bf16x8*)&KsP[((jt << 4) + l16) * 72 + (quad << 3)];
      f32x4 z = {};
      S[jt] = __builtin_amdgcn_mfma_f32_16x16x32_bf16(aq, bk, z, 0, 0, 0);
    }

    // ---- bias + online softmax
    float sv[4][4], mnew[4];
#pragma unroll
    for (int r = 0; r < 4; r++) mnew[r] = m_r[r];
#pragma unroll
    for (int jt = 0; jt < 4; jt++) {
      float2 pj = posT[(jt << 4) + l16];
      float by = -15.5f * pj.x;
      float bx = -15.5f * pj.y;
#pragma unroll
      for (int r = 0; r < 4; r++) {
        float ys = ay[r] + by, sx = ax[r] + bx;
        float y0f = floorf(ys), x0f = floorf(sx);
        float fy = ys - y0f, fx = sx - x0f;
        int iy0 = (int)y0f, ix0 = (int)x0f;
        int cy = min(max(iy0, -1), 62);
        int cx = min(max(ix0, -1), 62);
        int base = cy * 63 + cx;
        unsigned p0 = rpeU[base];        // (g00, g01)
        unsigned p1 = rpeU[base + 63];   // (g10, g11)
        float g00 = ubf_lo(p0), g01 = ubf_hi(p0);
        float g10 = ubf_lo(p1), g11 = ubf_hi(p1);
        float wx0 = ((unsigned)ix0 < 63u) ? (1.f - fx) : 0.f;
        float wx1 = ((unsigned)(ix0 + 1) < 63u) ? fx : 0.f;
        float wy0 = ((unsigned)iy0 < 63u) ? (1.f - fy) : 0.f;
        float wy1 = ((unsigned)(iy0 + 1) < 63u) ? fy : 0.f;
        float bias = wy0 * (wx0 * g00 + wx1 * g01) + wy1 * (wx0 * g10 + wx1 * g11);
        float s = S[jt][r] + bias;
        sv[jt][r] = s;
        mnew[r] = fmaxf(mnew[r], s);
      }
    }
#pragma unroll
    for (int r = 0; r < 4; r++) {
#pragma unroll
      for (int msk = 1; msk < 16; msk <<= 1)
        mnew[r] = fmaxf(mnew[r], __shfl_xor(mnew[r], msk));
    }
    float rowsum[4];
    short pb[4][4];
#pragma unroll
    for (int r = 0; r < 4; r++) {
      float alpha = __expf(m_r[r] - mnew[r]);
      m_r[r] = mnew[r];
      l_r[r] *= alpha;
      Oacc[0][r] *= alpha;
      Oacc[1][r] *= alpha;
      rowsum[r] = 0.f;
    }
#pragma unroll
    for (int jt = 0; jt < 4; jt++) {
#pragma unroll
      for (int r = 0; r < 4; r++) {
        float p = __expf(sv[jt][r] - m_r[r]);
        pb[jt][r] = f2bf(p);
        rowsum[r] += bf2f(pb[jt][r]);  // sum quantized p for PV consistency
      }
    }
#pragma unroll
    for (int r = 0; r < 4; r++) {
      float rs = rowsum[r];
#pragma unroll
      for (int msk = 1; msk < 16; msk <<= 1) rs += __shfl_xor(rs, msk);
      l_r[r] += rs;
    }

    __syncthreads();  // [b3] all waves done reading K before P overwrites it

    // P write (wave-local rows w*16..w*16+15)
#pragma unroll
    for (int jt = 0; jt < 4; jt++)
#pragma unroll
      for (int r = 0; r < 4; r++)
        KsP[((wv << 4) + (quad << 2) + r) * 72 + (jt << 4) + l16] = pb[jt][r];

    // ---- PV (A-frag rows wave-local; in-order DS + compiler waitcnt)
    bf16x8 pa0 = *(const bf16x8*)&KsP[((wv << 4) + l16) * 72 + (quad << 3)];
    bf16x8 pa1 = *(const bf16x8*)&KsP[((wv << 4) + l16) * 72 + 32 + (quad << 3)];
#pragma unroll
    for (int dt = 0; dt < 2; dt++) {
      bf16x8 vb0 = *(const bf16x8*)&Vt[((dt << 4) + l16) * 72 + (quad << 3)];
      bf16x8 vb1 = *(const bf16x8*)&Vt[((dt << 4) + l16) * 72 + 32 + (quad << 3)];
      Oacc[dt] = __builtin_amdgcn_mfma_f32_16x16x32_bf16(pa0, vb0, Oacc[dt], 0, 0, 0);
      Oacc[dt] = __builtin_amdgcn_mfma_f32_16x16x32_bf16(pa1, vb1, Oacc[dt], 0, 0, 0);
    }
  }

  // epilogue -> ao bf16
#pragma unroll
  for (int r = 0; r < 4; r++) {
    float inv = 1.f / l_r[r];
    int row = (it << 6) + (wv << 4) + (quad << 2) + r;
#pragma unroll
    for (int dt = 0; dt < 2; dt++) {
      ao[(size_t)((b << 10) + row) * 256 + (h << 5) + (dt << 4) + l16] =
          f2bf(Oacc[dt][r] * inv);
    }
  }
}

// ---------------------------------------------------------------------------
extern "C" void kernel_launch(void* const* d_in, const int* in_sizes, int n_in,
                              void* d_out, int out_size, void* d_ws, size_t ws_size,
                              hipStream_t stream) {
  (void)in_sizes; (void)n_in; (void)out_size; (void)ws_size;
  const float* x      = (const float*)d_in[0];
  const float* Wq     = (const float*)d_in[1];
  const float* Wkv    = (const float*)d_in[2];
  const float* conv_w = (const float*)d_in[3];
  const float* conv_b = (const float*)d_in[4];
  const float* ln_g   = (const float*)d_in[5];
  const float* ln_b   = (const float*)d_in[6];
  const float* Woff   = (const float*)d_in[7];
  const float* rpe    = (const float*)d_in[8];
  const float* Wout   = (const float*)d_in[9];
  const float* bout   = (const float*)d_in[10];
  float* out = (float*)d_out;

  float* ws   = (float*)d_ws;
  float* q    = ws;                        // 2,097,152 f32
  float* pos  = ws + 2097152;              //    32,768 f32
  short* kvb  = (short*)(ws + 2129920);    // 8192*512 bf16 (2,097,152 slots)
  short* xsb  = (short*)(ws + 4227072);    // 8192*256 bf16 (1,048,576 slots)
  short* aob  = (short*)(ws + 5275648);    // 8192*256 bf16 (1,048,576 slots)
  short* Wkvt = (short*)(ws + 6324224);    // 512*256 bf16
  short* Woutt= (short*)(ws + 6389760);    // 256*256 bf16

  prep_weights<<<768, 256, 0, stream>>>(Wkv, Wout, Wkvt, Woutt);
  // 1. q = x @ Wq (f32: feeds the pos-sensitive conv path)
  gemm_f32<<<dim3(4, 128), 256, 0, stream>>>(x, Wq, q, nullptr, 8192, 256, 256);
  // 2. conv + LN + GELU + Woff + tanh -> pos
  conv_pos_kernel<<<16384, 128, 0, stream>>>(q, conv_w, conv_b, ln_g, ln_b, Woff, pos);
  // 3. grid_sample -> xs (bf16)
  sample_kernel<<<8192, 256, 0, stream>>>(q, pos, xsb);
  // 4. kv = xs @ Wkv (bf16 MFMA, bf16 out)
  gemm_bf16<<<dim3(8, 128), 256, 0, stream>>>(xsb, Wkvt, nullptr, kvb, nullptr, 512);
  // 5. fused attention -> ao (bf16)
  attn_kernel<<<dim3(16, 8, 8), 256, 0, stream>>>(q, kvb, pos, rpe, aob);
  // 6. out = ao @ Wout + bout (bf16 MFMA, f32 out)
  gemm_bf16<<<dim3(4, 128), 256, 0, stream>>>(aob, Woutt, out, nullptr, bout, 256);
}

// Round 3
// 246.506 us; speedup vs baseline: 1.3496x; 1.1367x over previous
//
#include <hip/hip_runtime.h>
#include <hip/hip_bf16.h>

// DeformableAttention on MI355X.
// prep(weights^T bf16) -> gemm_bf16(q, f32-A staging) -> conv+LN+GELU->pos
// -> sample->xs(bf16) -> gemm_bf16(kv) -> fused flash-attn (fixed-m softmax,
// l via ones-MFMA, zero-padded rpe, exp2 domain) -> gemm_bf16(out,+bias)

#define EPS_ 1e-5f
#define ASCALE 0.17677669529663687f      // 1/sqrt(32)
#define LOG2E  1.4426950408889634f

typedef __attribute__((ext_vector_type(8))) short bf16x8;
typedef __attribute__((ext_vector_type(4))) short bf16x4;
typedef __attribute__((ext_vector_type(4))) float f32x4;

__device__ __forceinline__ short f2bf(float f) {
  union { float f; unsigned u; } v; v.f = f;
  unsigned r = (v.u + 0x7fffu + ((v.u >> 16) & 1u)) >> 16;  // RNE
  return (short)r;
}
__device__ __forceinline__ unsigned pk2bf(float a, float b) {
  union { __hip_bfloat162 h; unsigned u; } v;
  v.h = __float22bfloat162_rn(make_float2(a, b));
  return v.u;
}
__device__ __forceinline__ float ubf_lo(unsigned u) {
  union { unsigned u; float f; } v; v.u = u << 16; return v.f;
}
__device__ __forceinline__ float ubf_hi(unsigned u) {
  union { unsigned u; float f; } v; v.u = u & 0xffff0000u; return v.f;
}

// ---------------------------------------------------------------------------
// Weight prep: Wkvt[n][k]=bf16(Wkv[k][n]); Woutt, Wqt likewise (256x256).
// ---------------------------------------------------------------------------
__global__ __launch_bounds__(256) void prep_weights(
    const float* __restrict__ Wkv, const float* __restrict__ Wout,
    const float* __restrict__ Wq, short* __restrict__ Wkvt,
    short* __restrict__ Woutt, short* __restrict__ Wqt)
{
  int bid = blockIdx.x, k = threadIdx.x;
  if (bid < 512) Wkvt[bid * 256 + k] = f2bf(Wkv[k * 512 + bid]);
  else if (bid < 768) { int n = bid - 512; Woutt[n * 256 + k] = f2bf(Wout[k * 256 + n]); }
  else { int n = bid - 768; Wqt[n * 256 + k] = f2bf(Wq[k * 256 + n]); }
}

// ---------------------------------------------------------------------------
// bf16 MFMA GEMM: C[M,N] = A[M,256] @ Bt[N,256]^T (+bias).
// A from bf16 (Ab) or f32-with-staging-convert (Af). 64x64 tile, 256 thr.
// ---------------------------------------------------------------------------
__global__ __launch_bounds__(256) void gemm_bf16(
    const short* __restrict__ Ab, const float* __restrict__ Af,
    const short* __restrict__ Bt,
    float* __restrict__ Cf, short* __restrict__ Cb,
    const float* __restrict__ bias, int N)
{
  __shared__ __align__(16) short As[64 * 40];
  __shared__ __align__(16) short Bs[64 * 40];
  const int t = threadIdx.x;
  const int n0 = blockIdx.x << 6, m0 = blockIdx.y << 6;
  const int wv = t >> 6, l16 = t & 15, quad = (t & 63) >> 4;
  const int row = t >> 2, koff = (t & 3) << 3;
  f32x4 acc[4] = {};
  for (int k0 = 0; k0 < 256; k0 += 32) {
    bf16x8 av;
    if (Af) {
      const float* src = &Af[(size_t)(m0 + row) * 256 + k0 + koff];
      float4 f0 = *(const float4*)src;
      float4 f1 = *(const float4*)(src + 4);
      union { unsigned u[4]; bf16x8 v; } c;
      c.u[0] = pk2bf(f0.x, f0.y); c.u[1] = pk2bf(f0.z, f0.w);
      c.u[2] = pk2bf(f1.x, f1.y); c.u[3] = pk2bf(f1.z, f1.w);
      av = c.v;
    } else {
      av = *(const bf16x8*)&Ab[(size_t)(m0 + row) * 256 + k0 + koff];
    }
    bf16x8 bv = *(const bf16x8*)&Bt[(size_t)(n0 + row) * 256 + k0 + koff];
    __syncthreads();  // prior-iter frag reads done before overwrite
    *(bf16x8*)&As[row * 40 + koff] = av;
    *(bf16x8*)&Bs[row * 40 + koff] = bv;
    __syncthreads();
    bf16x8 a = *(const bf16x8*)&As[((wv << 4) + l16) * 40 + (quad << 3)];
#pragma unroll
    for (int jt = 0; jt < 4; jt++) {
      bf16x8 bb = *(const bf16x8*)&Bs[((jt << 4) + l16) * 40 + (quad << 3)];
      acc[jt] = __builtin_amdgcn_mfma_f32_16x16x32_bf16(a, bb, acc[jt], 0, 0, 0);
    }
  }
#pragma unroll
  for (int jt = 0; jt < 4; jt++) {
#pragma unroll
    for (int r = 0; r < 4; r++) {
      int mrow = m0 + (wv << 4) + (quad << 2) + r;
      int ncol = n0 + (jt << 4) + l16;
      float v = acc[jt][r];
      if (bias) v += bias[ncol];
      if (Cf) Cf[(size_t)mrow * N + ncol] = v;
      else    Cb[(size_t)mrow * N + ncol] = f2bf(v);
    }
  }
}

// ---------------------------------------------------------------------------
// conv5x5 depthwise + LN(128) + GELU + @Woff + tanh -> pos.
// One wave per pixel, 2 channels/lane, shfl-only reductions (no barriers).
// ---------------------------------------------------------------------------
__global__ __launch_bounds__(256) void conv_pos_kernel(
    const float* __restrict__ q, const float* __restrict__ conv_w,
    const float* __restrict__ conv_b, const float* __restrict__ ln_g,
    const float* __restrict__ ln_b, const float* __restrict__ Woff,
    float* __restrict__ pos)
{
  const int p = (blockIdx.x << 2) + (threadIdx.x >> 6);
  const int lane = threadIdx.x & 63;
  const int bg = p >> 10, pix = p & 1023;
  const int hh = pix >> 5, ww = pix & 31;
  const int b = bg >> 1, g = bg & 1;
  const int c0 = lane << 1;

  float2 cb = *(const float2*)&conv_b[c0];
  float a0 = cb.x, a1 = cb.y;
  const float* w0 = conv_w + c0 * 25;
  const float* w1 = w0 + 25;
#pragma unroll
  for (int dy = 0; dy < 5; dy++) {
    int y = hh + dy - 2;
    if ((unsigned)y < 32u) {
#pragma unroll
      for (int dx = 0; dx < 5; dx++) {
        int x = ww + dx - 2;
        if ((unsigned)x < 32u) {
          float2 qv = *(const float2*)&q[(size_t)((b << 10) + (y << 5) + x) * 256 + (g << 7) + c0];
          a0 = fmaf(qv.x, w0[dy * 5 + dx], a0);
          a1 = fmaf(qv.y, w1[dy * 5 + dx], a1);
        }
      }
    }
  }
  float s1 = a0 + a1, s2 = a0 * a0 + a1 * a1;
#pragma unroll
  for (int o = 32; o; o >>= 1) { s1 += __shfl_xor(s1, o); s2 += __shfl_xor(s2, o); }
  float mu = s1 * (1.f / 128.f);
  float inv = rsqrtf(fmaf(-mu, mu, s2 * (1.f / 128.f)) + EPS_);
  float2 lg = *(const float2*)&ln_g[c0];
  float2 lb = *(const float2*)&ln_b[c0];
  float v0 = (a0 - mu) * inv * lg.x + lb.x;
  float v1 = (a1 - mu) * inv * lg.y + lb.y;
  float ge0 = 0.5f * v0 * (1.f + erff(v0 * 0.70710678118654752f));
  float ge1 = 0.5f * v1 * (1.f + erff(v1 * 0.70710678118654752f));
  float2 W0 = *(const float2*)&Woff[c0 * 2];
  float2 W1 = *(const float2*)&Woff[c0 * 2 + 2];
  float o0 = ge0 * W0.x + ge1 * W1.x;
  float o1 = ge0 * W0.y + ge1 * W1.y;
#pragma unroll
  for (int o = 32; o; o >>= 1) { o0 += __shfl_xor(o0, o); o1 += __shfl_xor(o1, o); }
  if (lane == 0) {
    float py = tanhf(o0) * 0.0625f + ((hh + 0.5f) * 0.0625f - 1.f);
    float px = tanhf(o1) * 0.0625f + ((ww + 0.5f) * 0.0625f - 1.f);
    ((float2*)pos)[(bg << 10) + pix] = make_float2(py, px);
  }
}

// ---------------------------------------------------------------------------
// grid_sample -> xs (bf16). One wave per pixel, 4 channels/lane (float4).
// ---------------------------------------------------------------------------
__global__ __launch_bounds__(256) void sample_kernel(
    const float* __restrict__ q, const float* __restrict__ pos,
    short* __restrict__ xsb)
{
  const int p = (blockIdx.x << 2) + (threadIdx.x >> 6);
  const int lane = threadIdx.x & 63;
  const int n = p & 1023, b = p >> 10;
  const int d0 = lane << 2;
  const int g = lane >> 5;
  float2 pp = ((const float2*)pos)[(((b << 1) + g) << 10) + n];
  float x = (pp.y + 1.f) * 15.5f;
  float y = (pp.x + 1.f) * 15.5f;
  float x0f = floorf(x), y0f = floorf(y);
  int ix0 = (int)x0f, iy0 = (int)y0f;
  float fx = x - x0f, fy = y - y0f;
  float ac0 = 0.f, ac1 = 0.f, ac2 = 0.f, ac3 = 0.f;
#pragma unroll
  for (int dy = 0; dy < 2; dy++) {
#pragma unroll
    for (int dx = 0; dx < 2; dx++) {
      int yi = iy0 + dy, xi = ix0 + dx;
      float w = (dy ? fy : 1.f - fy) * (dx ? fx : 1.f - fx);
      if ((unsigned)yi < 32u && (unsigned)xi < 32u) {
        float4 qv = *(const float4*)&q[(size_t)((b << 10) + (yi << 5) + xi) * 256 + d0];
        ac0 = fmaf(w, qv.x, ac0); ac1 = fmaf(w, qv.y, ac1);
        ac2 = fmaf(w, qv.z, ac2); ac3 = fmaf(w, qv.w, ac3);
      }
    }
  }
  uint2 o;
  o.x = pk2bf(ac0, ac1);
  o.y = pk2bf(ac2, ac3);
  *(uint2*)&xsb[(size_t)((b << 10) + n) * 256 + d0] = o;
}

// ---------------------------------------------------------------------------
// Fused attention, fixed-m softmax (scores are tiny by construction):
//   p = exp2(S' + bias')  with S' = (q k)*ASCALE*log2e, bias' = rpe*log2e
//   l accumulated by MFMA against a constant all-ones B fragment.
// rpe staged zero-padded (67x67, origin +2) as packed bf16 x-pairs: the pads
// make OOB taps contribute 0 with no mask ops.  P aliased into K buffer.
// ---------------------------------------------------------------------------
__global__ __launch_bounds__(256) void attn_kernel(
    const float* __restrict__ q, const short* __restrict__ kvb,
    const float* __restrict__ pos, const float* __restrict__ rpe,
    short* __restrict__ ao)
{
  const int it = blockIdx.x, h = blockIdx.y, b = blockIdx.z;
  const int g = h >> 2, t = threadIdx.x;
  const int wv = t >> 6, l16 = t & 15, quad = (t & 63) >> 4;

  __shared__ __align__(16) short Qs[64 * 40];
  __shared__ __align__(16) short KsP[64 * 72];   // K tile, then P (aliased)
  __shared__ __align__(16) short Vt[32 * 72];    // V transposed [d][j]
  __shared__ float2 posT[64];
  __shared__ __align__(16) unsigned rpeU[67 * 67];  // padded, packed x-pairs

  // stage rpe: padded grid rows/cols -2..64, value*LOG2E, bf16 pair (x, x+1)
  for (int i = t; i < 4489; i += 256) {
    int prow = i / 67, pcol = i % 67;
    int ry = prow - 2, rx = pcol - 2;
    float v0 = 0.f, v1 = 0.f;
    if ((unsigned)ry < 63u) {
      const float* rp = rpe + h * 3969 + ry * 63;
      if ((unsigned)rx < 63u) v0 = rp[rx] * LOG2E;
      if ((unsigned)(rx + 1) < 63u) v1 = rp[rx + 1] * LOG2E;
    }
    rpeU[i] = pk2bf(v0, v1);
  }
  // stage Q (once), scaled by ASCALE*LOG2E, bf16
  {
    int i = t >> 2, dq = (t & 3) << 3;
    const float* src = q + (size_t)((b << 10) + (it << 6) + i) * 256 + (h << 5) + dq;
    float4 f0 = *(const float4*)src;
    float4 f1 = *(const float4*)(src + 4);
    const float sc = ASCALE * LOG2E;
    union { unsigned u[4]; bf16x8 v; } c;
    c.u[0] = pk2bf(f0.x * sc, f0.y * sc); c.u[1] = pk2bf(f0.z * sc, f0.w * sc);
    c.u[2] = pk2bf(f1.x * sc, f1.y * sc); c.u[3] = pk2bf(f1.z * sc, f1.w * sc);
    *(bf16x8*)&Qs[i * 40 + dq] = c.v;
  }

  // padded-origin bias coords: ys = ay[i] + by[j] (already includes +2 pad)
  float ay[4], ax[4];
#pragma unroll
  for (int r = 0; r < 4; r++) {
    int qi = (it << 6) + (wv << 4) + (quad << 2) + r;
    int iy = qi >> 5, ix = qi & 31;
    ay[r] = 15.5f * ((iy + 0.5f) * 0.0625f - 1.f) + 33.f;
    ax[r] = 15.5f * ((ix + 0.5f) * 0.0625f - 1.f) + 33.f;
  }

  bf16x8 vones;
#pragma unroll
  for (int i = 0; i < 8; i++) vones[i] = (short)0x3F80;  // bf16 1.0

  f32x4 Oacc[2] = {};
  f32x4 lacc = {};

  for (int kt = 0; kt < 16; kt++) {
    const int jb = kt << 6;
    __syncthreads();  // [b1] prior PV reads of KsP/Vt done
    {   // K tile: straight bf16 copy [j][32]
      int j = t >> 2, koff = (t & 3) << 3;
      bf16x8 kvv = *(const bf16x8*)&kvb[(size_t)((b << 10) + jb + j) * 512 + (h << 5) + koff];
      *(bf16x8*)&KsP[j * 72 + koff] = kvv;
    }
#pragma unroll
    for (int iter = 0; iter < 2; iter++) {  // V transposed [d][j]
      int j = (t >> 3) + (iter << 5), dv = (t & 7) << 2;
      bf16x4 vv = *(const bf16x4*)&kvb[(size_t)((b << 10) + jb + j) * 512 + 256 + (h << 5) + dv];
#pragma unroll
      for (int i2 = 0; i2 < 4; i2++) Vt[(dv + i2) * 72 + j] = vv[i2];
    }
    if (t < 64) posT[t] = ((const float2*)pos)[(((b << 1) + g) << 10) + jb + t];
    __syncthreads();  // [b2]

    // ---- QK^T (4 MFMA)
    bf16x8 aq = *(const bf16x8*)&Qs[((wv << 4) + l16) * 40 + (quad << 3)];
    f32x4 S[4];
#pragma unroll
    for (int jt = 0; jt < 4; jt++) {
      bf16x8 bk = *(const bf16x8*)&KsP[((jt << 4) + l16) * 72 + (quad << 3)];
      f32x4 z = {};
      S[jt] = __builtin_amdgcn_mfma_f32_16x16x32_bf16(aq, bk, z, 0, 0, 0);
    }

    // ---- bias + p = exp2(S+bias)  (no max tracking, no reductions)
    unsigned pu[4][2];
#pragma unroll
    for (int jt = 0; jt < 4; jt++) {
      float2 pj = posT[(jt << 4) + l16];
      float by = -15.5f * pj.x;
      float bx = -15.5f * pj.y;
      float pv[4];
#pragma unroll
      for (int r = 0; r < 4; r++) {
        float ys = ay[r] + by, sx = ax[r] + bx;
        float y0f = floorf(ys), x0f = floorf(sx);
        float fy = ys - y0f, fx = sx - x0f;
        int base = (int)y0f * 67 + (int)x0f;
        unsigned q0 = rpeU[base];        // (g00, g01)
        unsigned q1 = rpeU[base + 67];   // (g10, g11)
        float g00 = ubf_lo(q0), g01 = ubf_hi(q0);
        float g10 = ubf_lo(q1), g11 = ubf_hi(q1);
        float h0 = fmaf(fx, g01 - g00, g00);
        float h1 = fmaf(fx, g11 - g10, g10);
        float bias = fmaf(fy, h1 - h0, h0);
        pv[r] = exp2f(S[jt][r] + bias);
      }
      pu[jt][0] = pk2bf(pv[0], pv[1]);
      pu[jt][1] = pk2bf(pv[2], pv[3]);
    }

    __syncthreads();  // [b3] all waves done reading K before P overwrites it

    // P write (wave-local rows wv*16..wv*16+15)
#pragma unroll
    for (int jt = 0; jt < 4; jt++) {
      int cb = (jt << 4) + l16;
      int rb = ((wv << 4) + (quad << 2)) * 72 + cb;
      KsP[rb]       = (short)(pu[jt][0] & 0xffff);
      KsP[rb + 72]  = (short)(pu[jt][0] >> 16);
      KsP[rb + 144] = (short)(pu[jt][1] & 0xffff);
      KsP[rb + 216] = (short)(pu[jt][1] >> 16);
    }

    // ---- PV (4 MFMA) + l accumulation via ones B-frag (2 MFMA)
    bf16x8 pa0 = *(const bf16x8*)&KsP[((wv << 4) + l16) * 72 + (quad << 3)];
    bf16x8 pa1 = *(const bf16x8*)&KsP[((wv << 4) + l16) * 72 + 32 + (quad << 3)];
#pragma unroll
    for (int dt = 0; dt < 2; dt++) {
      bf16x8 vb0 = *(const bf16x8*)&Vt[((dt << 4) + l16) * 72 + (quad << 3)];
      bf16x8 vb1 = *(const bf16x8*)&Vt[((dt << 4) + l16) * 72 + 32 + (quad << 3)];
      Oacc[dt] = __builtin_amdgcn_mfma_f32_16x16x32_bf16(pa0, vb0, Oacc[dt], 0, 0, 0);
      Oacc[dt] = __builtin_amdgcn_mfma_f32_16x16x32_bf16(pa1, vb1, Oacc[dt], 0, 0, 0);
    }
    lacc = __builtin_amdgcn_mfma_f32_16x16x32_bf16(pa0, vones, lacc, 0, 0, 0);
    lacc = __builtin_amdgcn_mfma_f32_16x16x32_bf16(pa1, vones, lacc, 0, 0, 0);
  }

  // epilogue -> ao bf16 (every lane holds its rows' l in lacc)
#pragma unroll
  for (int r = 0; r < 4; r++) {
    float inv = 1.f / lacc[r];
    int row = (it << 6) + (wv << 4) + (quad << 2) + r;
#pragma unroll
    for (int dt = 0; dt < 2; dt++) {
      ao[(size_t)((b << 10) + row) * 256 + (h << 5) + (dt << 4) + l16] =
          f2bf(Oacc[dt][r] * inv);
    }
  }
}

// ---------------------------------------------------------------------------
extern "C" void kernel_launch(void* const* d_in, const int* in_sizes, int n_in,
                              void* d_out, int out_size, void* d_ws, size_t ws_size,
                              hipStream_t stream) {
  (void)in_sizes; (void)n_in; (void)out_size; (void)ws_size;
  const float* x      = (const float*)d_in[0];
  const float* Wq     = (const float*)d_in[1];
  const float* Wkv    = (const float*)d_in[2];
  const float* conv_w = (const float*)d_in[3];
  const float* conv_b = (const float*)d_in[4];
  const float* ln_g   = (const float*)d_in[5];
  const float* ln_b   = (const float*)d_in[6];
  const float* Woff   = (const float*)d_in[7];
  const float* rpe    = (const float*)d_in[8];
  const float* Wout   = (const float*)d_in[9];
  const float* bout   = (const float*)d_in[10];
  float* out = (float*)d_out;

  float* ws    = (float*)d_ws;
  float* q     = ws;                       // 2,097,152 f32
  float* pos   = ws + 2097152;             //    32,768 f32
  short* kvb   = (short*)(ws + 2129920);   // 8192*512 bf16
  short* xsb   = (short*)(ws + 4227072);   // 8192*256 bf16
  short* aob   = (short*)(ws + 5275648);   // 8192*256 bf16
  short* Wkvt  = (short*)(ws + 6324224);   // 512*256 bf16
  short* Woutt = (short*)(ws + 6389760);   // 256*256 bf16
  short* Wqt   = (short*)(ws + 6422528);   // 256*256 bf16

  prep_weights<<<1024, 256, 0, stream>>>(Wkv, Wout, Wq, Wkvt, Woutt, Wqt);
  // 1. q = x @ Wq (bf16 MFMA, f32 A staged+converted, f32 out)
  gemm_bf16<<<dim3(4, 128), 256, 0, stream>>>(nullptr, x, Wqt, q, nullptr, nullptr, 256);
  // 2. conv + LN + GELU + Woff + tanh -> pos
  conv_pos_kernel<<<4096, 256, 0, stream>>>(q, conv_w, conv_b, ln_g, ln_b, Woff, pos);
  // 3. grid_sample -> xs (bf16)
  sample_kernel<<<2048, 256, 0, stream>>>(q, pos, xsb);
  // 4. kv = xs @ Wkv (bf16 MFMA, bf16 out)
  gemm_bf16<<<dim3(8, 128), 256, 0, stream>>>(xsb, nullptr, Wkvt, nullptr, kvb, nullptr, 512);
  // 5. fused attention -> ao (bf16)
  attn_kernel<<<dim3(16, 8, 8), 256, 0, stream>>>(q, kvb, pos, rpe, aob);
  // 6. out = ao @ Wout + bout (bf16 MFMA, f32 out)
  gemm_bf16<<<dim3(4, 128), 256, 0, stream>>>(aob, nullptr, Woutt, out, nullptr, bout, 256);
}

// Round 4
// 236.879 us; speedup vs baseline: 1.4045x; 1.0406x over previous
//
#include <hip/hip_runtime.h>
#include <hip/hip_bf16.h>
#include <hip/hip_fp16.h>

// DeformableAttention on MI355X.
// prep(weights^T bf16) -> gemm_bf16(q) -> fused conv+LN+GELU+pos+sample ->
// gemm_bf16(kv) -> fused flash-attn (fixed-m softmax, l via ones-MFMA,
// f16 y-pair rpe table, pk-f16 lerp, exp2 domain) -> gemm_bf16(out,+bias)

#define EPS_ 1e-5f
#define ASCALE 0.17677669529663687f      // 1/sqrt(32)
#define LOG2E  1.4426950408889634f

typedef __attribute__((ext_vector_type(8))) short bf16x8;
typedef __attribute__((ext_vector_type(4))) short bf16x4;
typedef __attribute__((ext_vector_type(4))) float f32x4;

__device__ __forceinline__ short f2bf(float f) {
  union { float f; unsigned u; } v; v.f = f;
  unsigned r = (v.u + 0x7fffu + ((v.u >> 16) & 1u)) >> 16;  // RNE
  return (short)r;
}
__device__ __forceinline__ unsigned pk2bf(float a, float b) {
  union { __hip_bfloat162 h; unsigned u; } v;
  v.h = __float22bfloat162_rn(make_float2(a, b));
  return v.u;
}
__device__ __forceinline__ float exp2_fast(float x) {
  return __builtin_amdgcn_exp2f(x);   // raw v_exp_f32
}

// ---------------------------------------------------------------------------
// Weight prep: Wkvt[n][k]=bf16(Wkv[k][n]); Woutt, Wqt likewise.
// ---------------------------------------------------------------------------
__global__ __launch_bounds__(256) void prep_weights(
    const float* __restrict__ Wkv, const float* __restrict__ Wout,
    const float* __restrict__ Wq, short* __restrict__ Wkvt,
    short* __restrict__ Woutt, short* __restrict__ Wqt)
{
  int bid = blockIdx.x, k = threadIdx.x;
  if (bid < 512) Wkvt[bid * 256 + k] = f2bf(Wkv[k * 512 + bid]);
  else if (bid < 768) { int n = bid - 512; Woutt[n * 256 + k] = f2bf(Wout[k * 256 + n]); }
  else { int n = bid - 768; Wqt[n * 256 + k] = f2bf(Wq[k * 256 + n]); }
}

// ---------------------------------------------------------------------------
// bf16 MFMA GEMM: C[M,N] = A[M,256] @ Bt[N,256]^T (+bias).
// A from bf16 (Ab) or f32-with-staging-convert (Af). 64x64 tile, 256 thr.
// ---------------------------------------------------------------------------
__global__ __launch_bounds__(256) void gemm_bf16(
    const short* __restrict__ Ab, const float* __restrict__ Af,
    const short* __restrict__ Bt,
    float* __restrict__ Cf, short* __restrict__ Cb,
    const float* __restrict__ bias, int N)
{
  __shared__ __align__(16) short As[64 * 40];
  __shared__ __align__(16) short Bs[64 * 40];
  const int t = threadIdx.x;
  const int n0 = blockIdx.x << 6, m0 = blockIdx.y << 6;
  const int wv = t >> 6, l16 = t & 15, quad = (t & 63) >> 4;
  const int row = t >> 2, koff = (t & 3) << 3;
  f32x4 acc[4] = {};
  for (int k0 = 0; k0 < 256; k0 += 32) {
    bf16x8 av;
    if (Af) {
      const float* src = &Af[(size_t)(m0 + row) * 256 + k0 + koff];
      float4 f0 = *(const float4*)src;
      float4 f1 = *(const float4*)(src + 4);
      union { unsigned u[4]; bf16x8 v; } c;
      c.u[0] = pk2bf(f0.x, f0.y); c.u[1] = pk2bf(f0.z, f0.w);
      c.u[2] = pk2bf(f1.x, f1.y); c.u[3] = pk2bf(f1.z, f1.w);
      av = c.v;
    } else {
      av = *(const bf16x8*)&Ab[(size_t)(m0 + row) * 256 + k0 + koff];
    }
    bf16x8 bv = *(const bf16x8*)&Bt[(size_t)(n0 + row) * 256 + k0 + koff];
    __syncthreads();  // prior-iter frag reads done before overwrite
    *(bf16x8*)&As[row * 40 + koff] = av;
    *(bf16x8*)&Bs[row * 40 + koff] = bv;
    __syncthreads();
    bf16x8 a = *(const bf16x8*)&As[((wv << 4) + l16) * 40 + (quad << 3)];
#pragma unroll
    for (int jt = 0; jt < 4; jt++) {
      bf16x8 bb = *(const bf16x8*)&Bs[((jt << 4) + l16) * 40 + (quad << 3)];
      acc[jt] = __builtin_amdgcn_mfma_f32_16x16x32_bf16(a, bb, acc[jt], 0, 0, 0);
    }
  }
#pragma unroll
  for (int jt = 0; jt < 4; jt++) {
#pragma unroll
    for (int r = 0; r < 4; r++) {
      int mrow = m0 + (wv << 4) + (quad << 2) + r;
      int ncol = n0 + (jt << 4) + l16;
      float v = acc[jt][r];
      if (bias) v += bias[ncol];
      if (Cf) Cf[(size_t)mrow * N + ncol] = v;
      else    Cb[(size_t)mrow * N + ncol] = f2bf(v);
    }
  }
}

// ---------------------------------------------------------------------------
// Fused: conv5x5 depthwise + LN(128) + GELU + @Woff + tanh -> pos, then
// immediately grid_sample this pixel's group channels -> xs (bf16).
// One wave per (b, g, pixel); 2 channels/lane; butterfly reductions leave
// the sums in ALL lanes, so every lane has pos for the sampling step.
// ---------------------------------------------------------------------------
__global__ __launch_bounds__(256) void conv_pos_sample_kernel(
    const float* __restrict__ q, const float* __restrict__ conv_w,
    const float* __restrict__ conv_b, const float* __restrict__ ln_g,
    const float* __restrict__ ln_b, const float* __restrict__ Woff,
    float* __restrict__ pos, short* __restrict__ xsb)
{
  const int p = (blockIdx.x << 2) + (threadIdx.x >> 6);
  const int lane = threadIdx.x & 63;
  const int bg = p >> 10, pix = p & 1023;
  const int hh = pix >> 5, ww = pix & 31;
  const int b = bg >> 1, g = bg & 1;
  const int c0 = lane << 1;

  // ---- depthwise conv 5x5
  float2 cb = *(const float2*)&conv_b[c0];
  float a0 = cb.x, a1 = cb.y;
  const float* w0 = conv_w + c0 * 25;
  const float* w1 = w0 + 25;
#pragma unroll
  for (int dy = 0; dy < 5; dy++) {
    int y = hh + dy - 2;
    if ((unsigned)y < 32u) {
#pragma unroll
      for (int dx = 0; dx < 5; dx++) {
        int x = ww + dx - 2;
        if ((unsigned)x < 32u) {
          float2 qv = *(const float2*)&q[(size_t)((b << 10) + (y << 5) + x) * 256 + (g << 7) + c0];
          a0 = fmaf(qv.x, w0[dy * 5 + dx], a0);
          a1 = fmaf(qv.y, w1[dy * 5 + dx], a1);
        }
      }
    }
  }
  // ---- LN + GELU + offset projection
  float s1 = a0 + a1, s2 = a0 * a0 + a1 * a1;
#pragma unroll
  for (int o = 32; o; o >>= 1) { s1 += __shfl_xor(s1, o); s2 += __shfl_xor(s2, o); }
  float mu = s1 * (1.f / 128.f);
  float inv = rsqrtf(fmaf(-mu, mu, s2 * (1.f / 128.f)) + EPS_);
  float2 lg = *(const float2*)&ln_g[c0];
  float2 lb = *(const float2*)&ln_b[c0];
  float v0 = (a0 - mu) * inv * lg.x + lb.x;
  float v1 = (a1 - mu) * inv * lg.y + lb.y;
  float ge0 = 0.5f * v0 * (1.f + erff(v0 * 0.70710678118654752f));
  float ge1 = 0.5f * v1 * (1.f + erff(v1 * 0.70710678118654752f));
  float2 W0 = *(const float2*)&Woff[c0 * 2];
  float2 W1 = *(const float2*)&Woff[c0 * 2 + 2];
  float o0 = ge0 * W0.x + ge1 * W1.x;
  float o1 = ge0 * W0.y + ge1 * W1.y;
#pragma unroll
  for (int o = 32; o; o >>= 1) { o0 += __shfl_xor(o0, o); o1 += __shfl_xor(o1, o); }
  // o0/o1 are wave-uniform now
  float py = tanhf(o0) * 0.0625f + ((hh + 0.5f) * 0.0625f - 1.f);
  float px = tanhf(o1) * 0.0625f + ((ww + 0.5f) * 0.0625f - 1.f);
  if (lane == 0)
    ((float2*)pos)[(bg << 10) + pix] = make_float2(py, px);

  // ---- grid_sample this pixel's 128 group channels
  float x = (px + 1.f) * 15.5f;
  float y = (py + 1.f) * 15.5f;
  float x0f = floorf(x), y0f = floorf(y);
  int ix0 = (int)x0f, iy0 = (int)y0f;
  float fx = x - x0f, fy = y - y0f;
  float ac0 = 0.f, ac1 = 0.f;
#pragma unroll
  for (int dy = 0; dy < 2; dy++) {
#pragma unroll
    for (int dx = 0; dx < 2; dx++) {
      int yi = iy0 + dy, xi = ix0 + dx;
      float w = (dy ? fy : 1.f - fy) * (dx ? fx : 1.f - fx);
      if ((unsigned)yi < 32u && (unsigned)xi < 32u) {
        float2 qv = *(const float2*)&q[(size_t)((b << 10) + (yi << 5) + xi) * 256 + (g << 7) + c0];
        ac0 = fmaf(w, qv.x, ac0);
        ac1 = fmaf(w, qv.y, ac1);
      }
    }
  }
  *(unsigned*)&xsb[(size_t)((b << 10) + pix) * 256 + (g << 7) + c0] = pk2bf(ac0, ac1);
}

// ---------------------------------------------------------------------------
// Fused attention, fixed-m softmax: p = exp2(S' + bias'), l via ones-MFMA.
// rpe table in LDS as f16 y-pairs: entry(y,x) = (g(y,x), g(y+1,x)) * log2e,
// zero-padded (67x67, origin +2).  Per sample: 2 ds_read_b32 (x0 / x0+1, imm
// offset) -> one v_pk_fma_f16 x-lerp -> f32 y-lerp.  y-coords hoisted per jt
// (a wave's 16 rows share one raster row -> iy const).  P aliased into K.
// ---------------------------------------------------------------------------
__global__ __launch_bounds__(256) void attn_kernel(
    const float* __restrict__ q, const short* __restrict__ kvb,
    const float* __restrict__ pos, const float* __restrict__ rpe,
    short* __restrict__ ao)
{
  const int it = blockIdx.x, h = blockIdx.y, b = blockIdx.z;
  const int g = h >> 2, t = threadIdx.x;
  const int wv = t >> 6, l16 = t & 15, quad = (t & 63) >> 4;

  __shared__ __align__(16) short Qs[64 * 40];
  __shared__ __align__(16) short KsP[64 * 72];   // K tile, then P (aliased)
  __shared__ __align__(16) short Vt[32 * 72];    // V transposed [d][j]
  __shared__ float2 posT[64];
  __shared__ __align__(16) __half2 rpeH[67 * 67];  // (g(y,x), g(y+1,x))*log2e

  // stage rpe y-pair table (padded rows/cols -2..64; OOB -> 0)
  for (int i = t; i < 4489; i += 256) {
    int prow = i / 67, pcol = i % 67;
    int ry = prow - 2, rx = pcol - 2;
    float v0 = 0.f, v1 = 0.f;
    if ((unsigned)rx < 63u) {
      const float* cp = rpe + h * 3969 + rx;
      if ((unsigned)ry < 63u)       v0 = cp[ry * 63] * LOG2E;
      if ((unsigned)(ry + 1) < 63u) v1 = cp[(ry + 1) * 63] * LOG2E;
    }
    rpeH[i] = __floats2half2_rn(v0, v1);
  }
  // stage Q (once), scaled by ASCALE*LOG2E, bf16
  {
    int i = t >> 2, dq = (t & 3) << 3;
    const float* src = q + (size_t)((b << 10) + (it << 6) + i) * 256 + (h << 5) + dq;
    float4 f0 = *(const float4*)src;
    float4 f1 = *(const float4*)(src + 4);
    const float sc = ASCALE * LOG2E;
    union { unsigned u[4]; bf16x8 v; } c;
    c.u[0] = pk2bf(f0.x * sc, f0.y * sc); c.u[1] = pk2bf(f0.z * sc, f0.w * sc);
    c.u[2] = pk2bf(f1.x * sc, f1.y * sc); c.u[3] = pk2bf(f1.z * sc, f1.w * sc);
    *(bf16x8*)&Qs[i * 40 + dq] = c.v;
  }

  // wave's 16 rows lie in one raster row: iy const -> ayc scalar; ax per r
  const int row0 = (it << 6) + (wv << 4);
  const float ayc = 15.5f * (((row0 >> 5) + 0.5f) * 0.0625f - 1.f) + 33.f;
  float ax[4];
#pragma unroll
  for (int r = 0; r < 4; r++) {
    int ix = (row0 & 31) + (quad << 2) + r;
    ax[r] = 15.5f * ((ix + 0.5f) * 0.0625f - 1.f) + 33.f;
  }

  bf16x8 vones;
#pragma unroll
  for (int i = 0; i < 8; i++) vones[i] = (short)0x3F80;  // bf16 1.0

  f32x4 Oacc[2] = {};
  f32x4 lacc = {};

  for (int kt = 0; kt < 16; kt++) {
    const int jb = kt << 6;
    __syncthreads();  // [b1] prior PV reads of KsP/Vt done
    {   // K tile: straight bf16 copy [j][32]
      int j = t >> 2, koff = (t & 3) << 3;
      bf16x8 kvv = *(const bf16x8*)&kvb[(size_t)((b << 10) + jb + j) * 512 + (h << 5) + koff];
      *(bf16x8*)&KsP[j * 72 + koff] = kvv;
    }
#pragma unroll
    for (int iter = 0; iter < 2; iter++) {  // V transposed [d][j]
      int j = (t >> 3) + (iter << 5), dv = (t & 7) << 2;
      bf16x4 vv = *(const bf16x4*)&kvb[(size_t)((b << 10) + jb + j) * 512 + 256 + (h << 5) + dv];
#pragma unroll
      for (int i2 = 0; i2 < 4; i2++) Vt[(dv + i2) * 72 + j] = vv[i2];
    }
    if (t < 64) posT[t] = ((const float2*)pos)[(((b << 1) + g) << 10) + jb + t];
    __syncthreads();  // [b2]

    // ---- QK^T (4 MFMA)
    bf16x8 aq = *(const bf16x8*)&Qs[((wv << 4) + l16) * 40 + (quad << 3)];
    f32x4 S[4];
#pragma unroll
    for (int jt = 0; jt < 4; jt++) {
      bf16x8 bk = *(const bf16x8*)&KsP[((jt << 4) + l16) * 72 + (quad << 3)];
      f32x4 z = {};
      S[jt] = __builtin_amdgcn_mfma_f32_16x16x32_bf16(aq, bk, z, 0, 0, 0);
    }

    // ---- bias + p = exp2(S+bias)
    unsigned pu[4][2];
#pragma unroll
    for (int jt = 0; jt < 4; jt++) {
      float2 pj = posT[(jt << 4) + l16];
      // y-part shared by all 4 rows of this lane
      float ys = ayc - 15.5f * pj.x;
      float y0f = floorf(ys);
      float fy = ys - y0f;
      int ybase = (int)y0f * 67;
      float bx = -15.5f * pj.y;
      float pv[4];
#pragma unroll
      for (int r = 0; r < 4; r++) {
        float sx = ax[r] + bx;
        float x0f = floorf(sx);
        float fx = sx - x0f;
        int idx = ybase + (int)x0f;
        __half2 p0 = rpeH[idx];       // (g00, g10)
        __half2 p1 = rpeH[idx + 1];   // (g01, g11)
        __half2 fx2 = __float2half2_rn(fx);
        __half2 hh = __hfma2(fx2, __hsub2(p1, p0), p0);  // (h(y0), h(y0+1))
        float h0 = __low2float(hh), h1 = __high2float(hh);
        float bias = fmaf(fy, h1 - h0, h0);
        pv[r] = exp2_fast(S[jt][r] + bias);
      }
      pu[jt][0] = pk2bf(pv[0], pv[1]);
      pu[jt][1] = pk2bf(pv[2], pv[3]);
    }

    __syncthreads();  // [b3] all waves done reading K before P overwrites it

    // P write (wave-local rows wv*16..wv*16+15)
#pragma unroll
    for (int jt = 0; jt < 4; jt++) {
      int cb = (jt << 4) + l16;
      int rb = ((wv << 4) + (quad << 2)) * 72 + cb;
      KsP[rb]       = (short)(pu[jt][0] & 0xffff);
      KsP[rb + 72]  = (short)(pu[jt][0] >> 16);
      KsP[rb + 144] = (short)(pu[jt][1] & 0xffff);
      KsP[rb + 216] = (short)(pu[jt][1] >> 16);
    }

    // ---- PV (4 MFMA) + l accumulation via ones B-frag (2 MFMA)
    bf16x8 pa0 = *(const bf16x8*)&KsP[((wv << 4) + l16) * 72 + (quad << 3)];
    bf16x8 pa1 = *(const bf16x8*)&KsP[((wv << 4) + l16) * 72 + 32 + (quad << 3)];
#pragma unroll
    for (int dt = 0; dt < 2; dt++) {
      bf16x8 vb0 = *(const bf16x8*)&Vt[((dt << 4) + l16) * 72 + (quad << 3)];
      bf16x8 vb1 = *(const bf16x8*)&Vt[((dt << 4) + l16) * 72 + 32 + (quad << 3)];
      Oacc[dt] = __builtin_amdgcn_mfma_f32_16x16x32_bf16(pa0, vb0, Oacc[dt], 0, 0, 0);
      Oacc[dt] = __builtin_amdgcn_mfma_f32_16x16x32_bf16(pa1, vb1, Oacc[dt], 0, 0, 0);
    }
    lacc = __builtin_amdgcn_mfma_f32_16x16x32_bf16(pa0, vones, lacc, 0, 0, 0);
    lacc = __builtin_amdgcn_mfma_f32_16x16x32_bf16(pa1, vones, lacc, 0, 0, 0);
  }

  // epilogue -> ao bf16 (every lane holds its rows' l in lacc)
#pragma unroll
  for (int r = 0; r < 4; r++) {
    float inv = 1.f / lacc[r];
    int row = (it << 6) + (wv << 4) + (quad << 2) + r;
#pragma unroll
    for (int dt = 0; dt < 2; dt++) {
      ao[(size_t)((b << 10) + row) * 256 + (h << 5) + (dt << 4) + l16] =
          f2bf(Oacc[dt][r] * inv);
    }
  }
}

// ---------------------------------------------------------------------------
extern "C" void kernel_launch(void* const* d_in, const int* in_sizes, int n_in,
                              void* d_out, int out_size, void* d_ws, size_t ws_size,
                              hipStream_t stream) {
  (void)in_sizes; (void)n_in; (void)out_size; (void)ws_size;
  const float* x      = (const float*)d_in[0];
  const float* Wq     = (const float*)d_in[1];
  const float* Wkv    = (const float*)d_in[2];
  const float* conv_w = (const float*)d_in[3];
  const float* conv_b = (const float*)d_in[4];
  const float* ln_g   = (const float*)d_in[5];
  const float* ln_b   = (const float*)d_in[6];
  const float* Woff   = (const float*)d_in[7];
  const float* rpe    = (const float*)d_in[8];
  const float* Wout   = (const float*)d_in[9];
  const float* bout   = (const float*)d_in[10];
  float* out = (float*)d_out;

  float* ws    = (float*)d_ws;
  float* q     = ws;                       // 2,097,152 f32
  float* pos   = ws + 2097152;             //    32,768 f32
  short* kvb   = (short*)(ws + 2129920);   // 8192*512 bf16
  short* xsb   = (short*)(ws + 4227072);   // 8192*256 bf16
  short* aob   = (short*)(ws + 5275648);   // 8192*256 bf16
  short* Wkvt  = (short*)(ws + 6324224);   // 512*256 bf16
  short* Woutt = (short*)(ws + 6389760);   // 256*256 bf16
  short* Wqt   = (short*)(ws + 6422528);   // 256*256 bf16

  prep_weights<<<1024, 256, 0, stream>>>(Wkv, Wout, Wq, Wkvt, Woutt, Wqt);
  // 1. q = x @ Wq (bf16 MFMA, f32 A staged+converted, f32 out)
  gemm_bf16<<<dim3(4, 128), 256, 0, stream>>>(nullptr, x, Wqt, q, nullptr, nullptr, 256);
  // 2+3. conv + LN + GELU + Woff + tanh -> pos, fused grid_sample -> xs
  conv_pos_sample_kernel<<<4096, 256, 0, stream>>>(q, conv_w, conv_b, ln_g, ln_b,
                                                   Woff, pos, xsb);
  // 4. kv = xs @ Wkv (bf16 MFMA, bf16 out)
  gemm_bf16<<<dim3(8, 128), 256, 0, stream>>>(xsb, nullptr, Wkvt, nullptr, kvb, nullptr, 512);
  // 5. fused attention -> ao (bf16)
  attn_kernel<<<dim3(16, 8, 8), 256, 0, stream>>>(q, kvb, pos, rpe, aob);
  // 6. out = ao @ Wout + bout (bf16 MFMA, f32 out)
  gemm_bf16<<<dim3(4, 128), 256, 0, stream>>>(aob, nullptr, Woutt, out, nullptr, bout, 256);
}